// Round 11
// baseline (24.929 us; speedup 1.0000x reference)
//
#include <hip/hip_runtime.h>

// ResonantHTT embedding via two pair tables (b-major layout):
//   T[p01][b][u] = sum_a core0[i0,0,a,D0]*cos(phase[a]) * core1[i1,a,b,d1]
//   F[p23][b][v] = sum_c core2[i2,b,c,d2] * core3[i3,c,0,d3]
// Per token: out[n, u*16+v] = sum_b T[p01][b][u] * F[p23][b][v]
// k_out8 = R10 hybrid (T in regs, F via LDS) + 2-token software pipeline:
// both tokens' loads issue up front (one barrier), then
// compute A -> store A -> compute B -> store B, so NT stores of A overlap
// compute of B and the chip sees mixed read/write traffic instead of
// phase-locked all-read then all-write bursts.

typedef float f32x4 __attribute__((ext_vector_type(4)));

__global__ __launch_bounds__(256) void k_tables(
    const float* __restrict__ core0, const float* __restrict__ core1,
    const float* __restrict__ core2, const float* __restrict__ core3,
    const float* __restrict__ phase,
    float* __restrict__ T, float* __restrict__ F)
{
  const int gid = blockIdx.x * 256 + threadIdx.x;
  const int lane = threadIdx.x & 63;
  // each 16-lane segment holds cos(phase[0..15]); shuffle per a
  const float cown = cosf(phase[lane & 15]);
  if (blockIdx.x < 1024) {
    // ---- T: 262144 outputs, one per thread, coalesced b-major write ----
    const int p01 = gid >> 10, r = gid & 1023;
    const int b = r >> 6, u = r & 63;
    const int D0 = u >> 3, d1 = u & 7;
    const int i0 = p01 >> 4, i1 = p01 & 15;
    const float* c0 = core0 + i0 * 128 + D0;          // [a] stride 8
    const float* c1 = core1 + i1 * 2048 + b * 8 + d1; // [a] stride 128
    float acc = 0.f;
    #pragma unroll
    for (int a = 0; a < 16; ++a) {
      const float ca = __shfl(cown, a, 16);
      acc += c0[a * 8] * ca * c1[a * 128];
    }
    T[p01 * 1024 + b * 64 + u] = acc;
  } else {
    // ---- F: 65536 outputs, one per thread, coalesced b-major write ----
    const int o = gid - 262144;
    const int p23 = o >> 8, r = o & 255;
    const int b = r >> 4, v = r & 15;
    const int d2 = v >> 2, d3 = v & 3;
    const int i2 = p23 >> 4, i3 = p23 & 15;
    const float* c2 = core2 + i2 * 1024 + b * 64 + d2; // [c] stride 4
    const float* c3 = core3 + i3 * 64 + d3;            // [c] stride 4
    float acc = 0.f;
    #pragma unroll
    for (int c = 0; c < 16; ++c)
      acc += c2[c * 4] * c3[c * 4];
    F[p23 * 256 + b * 16 + v] = acc;
  }
}

__global__ __launch_bounds__(256, 3) void k_out8(
    const int* __restrict__ ids, const float* __restrict__ T,
    const float* __restrict__ F, float* __restrict__ out)
{
  __shared__ float sF[8][256];                  // 1KB per wave-token
  const int wv = threadIdx.x >> 6, lane = threadIdx.x & 63;
  const int nA = blockIdx.x * 8 + wv;           // wave's token A
  const int nB = nA + 4;                        // wave's token B
  const int idA = ids[nA], idB = ids[nB];       // wave-uniform
  const int ug = lane >> 2, vg = lane & 3;      // lane's 4x4 (u,v) tile

  // ---- stage both F-rows (1 coalesced 1KB load each) into LDS ----
  float* tFA = sF[wv];
  float* tFB = sF[wv + 4];
  {
    const f32x4 vA = *reinterpret_cast<const f32x4*>(F + (idA & 255) * 256 + lane * 4);
    *reinterpret_cast<f32x4*>(tFA + lane * 4) = vA;
    const f32x4 vB = *reinterpret_cast<const f32x4*>(F + (idB & 255) * 256 + lane * 4);
    *reinterpret_cast<f32x4*>(tFB + lane * 4) = vB;
  }

  // ---- both T-slices into registers: 32 independent coalesced loads ----
  f32x4 tregA[16], tregB[16];
  const float* TpA = T + (idA >> 8) * 1024 + ug * 4;
  const float* TpB = T + (idB >> 8) * 1024 + ug * 4;
  #pragma unroll
  for (int b = 0; b < 16; ++b) {
    tregA[b] = *reinterpret_cast<const f32x4*>(TpA + b * 64);
    tregB[b] = *reinterpret_cast<const f32x4*>(TpB + b * 64);
  }
  __syncthreads();   // cross-lane LDS RAW ordering (drains loads too)

  // ---- token A: compute + store ----
  {
    float acc[4][4];
    #pragma unroll
    for (int i = 0; i < 4; ++i)
      #pragma unroll
      for (int j = 0; j < 4; ++j) acc[i][j] = 0.f;
    #pragma unroll
    for (int b = 0; b < 16; ++b) {
      const f32x4 f = *reinterpret_cast<const f32x4*>(tFA + b * 16 + vg * 4);
      const f32x4 t = tregA[b];
      acc[0][0] += t.x*f.x; acc[0][1] += t.x*f.y; acc[0][2] += t.x*f.z; acc[0][3] += t.x*f.w;
      acc[1][0] += t.y*f.x; acc[1][1] += t.y*f.y; acc[1][2] += t.y*f.z; acc[1][3] += t.y*f.w;
      acc[2][0] += t.z*f.x; acc[2][1] += t.z*f.y; acc[2][2] += t.z*f.z; acc[2][3] += t.z*f.w;
      acc[3][0] += t.w*f.x; acc[3][1] += t.w*f.y; acc[3][2] += t.w*f.z; acc[3][3] += t.w*f.w;
    }
    float* op = out + (size_t)nA * 1024 + ug * 64 + vg * 4;
    #pragma unroll
    for (int i = 0; i < 4; ++i) {
      f32x4 v4 = { acc[i][0], acc[i][1], acc[i][2], acc[i][3] };
      __builtin_nontemporal_store(v4, reinterpret_cast<f32x4*>(op + i * 16));
    }
  }

  // ---- token B: compute (overlaps A's in-flight stores) + store ----
  {
    float acc[4][4];
    #pragma unroll
    for (int i = 0; i < 4; ++i)
      #pragma unroll
      for (int j = 0; j < 4; ++j) acc[i][j] = 0.f;
    #pragma unroll
    for (int b = 0; b < 16; ++b) {
      const f32x4 f = *reinterpret_cast<const f32x4*>(tFB + b * 16 + vg * 4);
      const f32x4 t = tregB[b];
      acc[0][0] += t.x*f.x; acc[0][1] += t.x*f.y; acc[0][2] += t.x*f.z; acc[0][3] += t.x*f.w;
      acc[1][0] += t.y*f.x; acc[1][1] += t.y*f.y; acc[1][2] += t.y*f.z; acc[1][3] += t.y*f.w;
      acc[2][0] += t.z*f.x; acc[2][1] += t.z*f.y; acc[2][2] += t.z*f.z; acc[2][3] += t.z*f.w;
      acc[3][0] += t.w*f.x; acc[3][1] += t.w*f.y; acc[3][2] += t.w*f.z; acc[3][3] += t.w*f.w;
    }
    float* op = out + (size_t)nB * 1024 + ug * 64 + vg * 4;
    #pragma unroll
    for (int i = 0; i < 4; ++i) {
      f32x4 v4 = { acc[i][0], acc[i][1], acc[i][2], acc[i][3] };
      __builtin_nontemporal_store(v4, reinterpret_cast<f32x4*>(op + i * 16));
    }
  }
}

extern "C" void kernel_launch(void* const* d_in, const int* in_sizes, int n_in,
                              void* d_out, int out_size, void* d_ws, size_t ws_size,
                              hipStream_t stream) {
  const int*   ids   = (const int*)  d_in[0];
  const float* core0 = (const float*)d_in[1];
  const float* core1 = (const float*)d_in[2];
  const float* core2 = (const float*)d_in[3];
  const float* core3 = (const float*)d_in[4];
  const float* phase = (const float*)d_in[5];
  float* out = (float*)d_out;

  float* Tt = (float*)d_ws;                    // 1 MB
  float* Ft = (float*)d_ws + 262144;           // 256 KB

  const int tokens = in_sizes[0];              // 16384
  hipLaunchKernelGGL(k_tables, dim3(1280), dim3(256), 0, stream,
                     core0, core1, core2, core3, phase, Tt, Ft);
  hipLaunchKernelGGL(k_out8, dim3(tokens / 8), dim3(256), 0, stream,
                     ids, Tt, Ft, out);
}

// Round 12
// 23.933 us; speedup vs baseline: 1.0416x; 1.0416x over previous
//
#include <hip/hip_runtime.h>

// ResonantHTT embedding via two pair tables (b-major layout, u-permuted T):
//   T[p01][b][us] = sum_a core0[i0,0,a,D0]*cos(phase[a]) * core1[i1,a,b,d1]
//       where us = (u>>4) + (u&15)*4  (u = D0*8+d1), p01 = i0*16+i1
//       -> 256 x 16 x 64 f32 = 1 MB
//   F[p23][b][v] = sum_c core2[i2,b,c,d2] * core3[i3,c,0,d3]
//       p23 = i2*16+i3, v = d2*4+d3   -> 256 x 16 x 16 f32 = 256 KB
// Per token: out[n, u*16+v] = sum_b T[p01][b][us(u)] * F[p23][b][v]
// k_out9: one token/wave; T in regs (16 coalesced f32x4 loads), F via LDS
// (1 coalesced 1KB load + conflict-free broadcast ds_reads). The u-permute
// makes each of the 4 output stores a fully CONTIGUOUS 1KB nontemporal
// store (complete 64B lines per instruction — no L2 strip-merge needed).

typedef float f32x4 __attribute__((ext_vector_type(4)));

__global__ __launch_bounds__(256) void k_tables(
    const float* __restrict__ core0, const float* __restrict__ core1,
    const float* __restrict__ core2, const float* __restrict__ core3,
    const float* __restrict__ phase,
    float* __restrict__ T, float* __restrict__ F)
{
  const int gid = blockIdx.x * 256 + threadIdx.x;
  const int lane = threadIdx.x & 63;
  // each 16-lane segment holds cos(phase[0..15]); shuffle per a
  const float cown = cosf(phase[lane & 15]);
  if (blockIdx.x < 1024) {
    // ---- T: 262144 outputs, one per thread, b-major + u-permuted write ----
    const int p01 = gid >> 10, r = gid & 1023;
    const int b = r >> 6, u = r & 63;
    const int D0 = u >> 3, d1 = u & 7;
    const int i0 = p01 >> 4, i1 = p01 & 15;
    const float* c0 = core0 + i0 * 128 + D0;          // [a] stride 8
    const float* c1 = core1 + i1 * 2048 + b * 8 + d1; // [a] stride 128
    float acc = 0.f;
    #pragma unroll
    for (int a = 0; a < 16; ++a) {
      const float ca = __shfl(cown, a, 16);
      acc += c0[a * 8] * ca * c1[a * 128];
    }
    const int us = (u >> 4) + (u & 15) * 4;           // store-permutation
    T[p01 * 1024 + b * 64 + us] = acc;
  } else {
    // ---- F: 65536 outputs, one per thread, coalesced b-major write ----
    const int o = gid - 262144;
    const int p23 = o >> 8, r = o & 255;
    const int b = r >> 4, v = r & 15;
    const int d2 = v >> 2, d3 = v & 3;
    const int i2 = p23 >> 4, i3 = p23 & 15;
    const float* c2 = core2 + i2 * 1024 + b * 64 + d2; // [c] stride 4
    const float* c3 = core3 + i3 * 64 + d3;            // [c] stride 4
    float acc = 0.f;
    #pragma unroll
    for (int c = 0; c < 16; ++c)
      acc += c2[c * 4] * c3[c * 4];
    F[p23 * 256 + b * 16 + v] = acc;
  }
}

__global__ __launch_bounds__(256) void k_out9(
    const int* __restrict__ ids, const float* __restrict__ T,
    const float* __restrict__ F, float* __restrict__ out)
{
  __shared__ float sF[4][256];                  // 1KB per wave
  const int wv = threadIdx.x >> 6, lane = threadIdx.x & 63;
  const int n = blockIdx.x * 4 + wv;            // one token per wave
  const int id = ids[n];                        // wave-uniform
  const int p01 = id >> 8, p23 = id & 255;
  const int ug = lane >> 2, vg = lane & 3;

  // ---- T-slice into registers: 16 coalesced float4 loads (independent).
  // treg[b][e] = T[p01][b][ug*4+e] which is actual u = e*16 + ug.
  f32x4 treg[16];
  const float* Tp = T + p01 * 1024 + ug * 4;
  #pragma unroll
  for (int b = 0; b < 16; ++b)
    treg[b] = *reinterpret_cast<const f32x4*>(Tp + b * 64);

  // ---- F-row (1KB): ONE coalesced load -> wave-private LDS ----
  float* tF = sF[wv];
  {
    const f32x4 v = *reinterpret_cast<const f32x4*>(F + p23 * 256 + lane * 4);
    *reinterpret_cast<f32x4*>(tF + lane * 4) = v;
  }
  __syncthreads();   // cross-lane LDS RAW ordering (R7 lesson)

  float acc[4][4];   // acc[e][j]: u = e*16+ug, v = vg*4+j
  #pragma unroll
  for (int i = 0; i < 4; ++i)
    #pragma unroll
    for (int j = 0; j < 4; ++j) acc[i][j] = 0.f;

  #pragma unroll
  for (int b = 0; b < 16; ++b) {
    // 4 distinct 16B segments, 16-way same-addr broadcast: conflict-free
    const f32x4 f = *reinterpret_cast<const f32x4*>(tF + b * 16 + vg * 4);
    const f32x4 t = treg[b];
    acc[0][0] += t.x*f.x; acc[0][1] += t.x*f.y; acc[0][2] += t.x*f.z; acc[0][3] += t.x*f.w;
    acc[1][0] += t.y*f.x; acc[1][1] += t.y*f.y; acc[1][2] += t.y*f.z; acc[1][3] += t.y*f.w;
    acc[2][0] += t.z*f.x; acc[2][1] += t.z*f.y; acc[2][2] += t.z*f.z; acc[2][3] += t.z*f.w;
    acc[3][0] += t.w*f.x; acc[3][1] += t.w*f.y; acc[3][2] += t.w*f.z; acc[3][3] += t.w*f.w;
  }

  // Output position for acc[e][j]: u*16+v = (e*16+ug)*16 + vg*4+j
  //   = e*256 + ug*16 + vg*4 + j = e*256 + lane*4 + j.
  // -> store e is 64 lanes x 16B CONTIGUOUS = 1KB, full 64B lines.
  float* op = out + (size_t)n * 1024 + lane * 4;
  #pragma unroll
  for (int e = 0; e < 4; ++e) {
    f32x4 v4 = { acc[e][0], acc[e][1], acc[e][2], acc[e][3] };
    __builtin_nontemporal_store(v4, reinterpret_cast<f32x4*>(op + e * 256));
  }
}

extern "C" void kernel_launch(void* const* d_in, const int* in_sizes, int n_in,
                              void* d_out, int out_size, void* d_ws, size_t ws_size,
                              hipStream_t stream) {
  const int*   ids   = (const int*)  d_in[0];
  const float* core0 = (const float*)d_in[1];
  const float* core1 = (const float*)d_in[2];
  const float* core2 = (const float*)d_in[3];
  const float* core3 = (const float*)d_in[4];
  const float* phase = (const float*)d_in[5];
  float* out = (float*)d_out;

  float* Tt = (float*)d_ws;                    // 1 MB
  float* Ft = (float*)d_ws + 262144;           // 256 KB

  const int tokens = in_sizes[0];              // 16384
  hipLaunchKernelGGL(k_tables, dim3(1280), dim3(256), 0, stream,
                     core0, core1, core2, core3, phase, Tt, Ft);
  hipLaunchKernelGGL(k_out9, dim3(tokens / 4), dim3(256), 0, stream,
                     ids, Tt, Ft, out);
}